// Round 9
// baseline (253.143 us; speedup 1.0000x reference)
//
#include <hip/hip_runtime.h>

typedef unsigned short u16;
typedef short bf16x8 __attribute__((ext_vector_type(8)));
typedef float f32x4 __attribute__((ext_vector_type(4)));
typedef float f32x16 __attribute__((ext_vector_type(16)));

#define B_  4
#define T_  2048
#define C_  1024
#define NH_ 16
#define HD_ 64

// async global->LDS, 16B/lane; LDS dest = wave-uniform base + lane*16.
__device__ __forceinline__ void gload16(const u16* g, u16* lds) {
  __builtin_amdgcn_global_load_lds(
      (const __attribute__((address_space(1))) void*)g,
      (__attribute__((address_space(3))) void*)lds, 16, 0, 0);
}

__device__ __forceinline__ u16 f2bf(float f) {  // RNE float->bf16
  union { float f; unsigned u; } x; x.f = f;
  unsigned r = x.u + 0x7fffu + ((x.u >> 16) & 1u);
  return (u16)(r >> 16);
}

__device__ __forceinline__ float max3f(float a, float b, float c) {
  return fmaxf(fmaxf(a, b), c);   // clang fuses to v_max3_f32
}

// v_permlane32_swap_b32: used ONLY for the P-fragment shuffle (distinct-value
// operands, verified rounds 3-5). Round 6 showed same-value cross-half
// reductions via PSWAP produce NaN — those use __shfl_xor(,32).
#define PSWAP(a, b) asm("v_permlane32_swap_b32 %0, %1" : "+v"(a), "+v"(b))

// ---------------------------------------------------------------------------
// x (f32, all batches) -> bf16
// ---------------------------------------------------------------------------
__global__ __launch_bounds__(256) void convert_x(const float* __restrict__ in,
                                                 u16* __restrict__ out) {
  int i = (blockIdx.x * 256 + threadIdx.x) * 8;
  float4 a = *(const float4*)(in + i);
  float4 b = *(const float4*)(in + i + 4);
  u16 t[8] = {f2bf(a.x), f2bf(a.y), f2bf(a.z), f2bf(a.w),
              f2bf(b.x), f2bf(b.y), f2bf(b.z), f2bf(b.w)};
  *(uint4*)(out + i) = *(const uint4*)t;
}

// ---------------------------------------------------------------------------
// Weight transpose+convert: f32 [R][Cc] -> bf16 [Cc][R]
// ---------------------------------------------------------------------------
__global__ __launch_bounds__(256) void transpose_w(const float* __restrict__ in,
                                                   u16* __restrict__ out,
                                                   int R, int Cc) {
  int r0 = blockIdx.x * 64, c0 = blockIdx.y * 64;
  __shared__ __attribute__((aligned(16))) u16 tile[64][72];
  int tid = threadIdx.x;
#pragma unroll
  for (int it = 0; it < 4; ++it) {
    int chunk = it * 256 + tid;          // 0..1023
    int row = chunk >> 4, c4 = chunk & 15;
    float4 v = *(const float4*)(in + (size_t)(r0 + row) * Cc + c0 + c4 * 4);
    tile[row][c4 * 4 + 0] = f2bf(v.x);
    tile[row][c4 * 4 + 1] = f2bf(v.y);
    tile[row][c4 * 4 + 2] = f2bf(v.z);
    tile[row][c4 * 4 + 3] = f2bf(v.w);
  }
  __syncthreads();
#pragma unroll
  for (int it = 0; it < 2; ++it) {
    int chunk = it * 256 + tid;
    int row = chunk >> 3, c8 = chunk & 7;
    uint4 v; u16* tv = (u16*)&v;
#pragma unroll
    for (int k = 0; k < 8; ++k) tv[k] = tile[c8 * 8 + k][row];
    *(uint4*)(out + (size_t)(c0 + row) * R + r0 + c8 * 8) = v;
  }
}

// ---------------------------------------------------------------------------
// Deep-prefetch BT GEMM mainloop: 128x256 tile, BK=64, 8 waves (2Mx4N),
// 3 LDS K-tile buffers (144KB), prefetch distance 2, counted vmcnt(6) +
// raw s_barrier (never drains the pipe — removes the m97 barrier stall).
// LDS XOR-swizzle (c ^= row&7) via pre-swizzled global source (rule #21).
// 32 MFMA per barrier per wave. Tail stages garbage into dead buffers so
// vmcnt counts stay compile-time uniform (reads stay inside d_ws).
// ---------------------------------------------------------------------------
__device__ __forceinline__ void gemm_mainloop(const u16* __restrict__ A,
                                              const u16* __restrict__ Bt,
                                              int m0, int n0,
                                              u16* sA0, u16* sA1, u16* sA2,
                                              u16* sB0, u16* sB1, u16* sB2,
                                              f32x4 acc[4][4]) {
  int tid = threadIdx.x;
  int w = tid >> 6, l = tid & 63, li = l & 15, quad = l >> 4;
  int wr = w >> 2, wc = w & 3;

  f32x4 zero = {0.f, 0.f, 0.f, 0.f};
#pragma unroll
  for (int m = 0; m < 4; ++m)
#pragma unroll
    for (int n = 0; n < 4; ++n) acc[m][n] = zero;

  // staging: 64 rows per gload issue; 8 chunks of 16B per 128B row.
  int srow = tid >> 3;                     // 0..63
  int sc = (tid & 7) ^ (srow & 7);         // pre-swizzled source chunk
  const u16* aS0 = A + (size_t)(m0 + srow) * C_ + sc * 8;
  const u16* aS1 = A + (size_t)(m0 + 64 + srow) * C_ + sc * 8;
  const u16* bS0 = Bt + (size_t)(n0 + srow) * C_ + sc * 8;
  const u16* bS1 = Bt + (size_t)(n0 + 64 + srow) * C_ + sc * 8;
  const u16* bS2 = Bt + (size_t)(n0 + 128 + srow) * C_ + sc * 8;
  const u16* bS3 = Bt + (size_t)(n0 + 192 + srow) * C_ + sc * 8;
  int ldOff = tid * 8;

#define STAGE6(sa, sb)                                   \
  {                                                      \
    gload16(aS0, (sa) + ldOff);                          \
    gload16(aS1, (sa) + 4096 + ldOff);                   \
    gload16(bS0, (sb) + ldOff);                          \
    gload16(bS1, (sb) + 4096 + ldOff);                   \
    gload16(bS2, (sb) + 8192 + ldOff);                   \
    gload16(bS3, (sb) + 12288 + ldOff);                  \
    aS0 += 64; aS1 += 64;                                \
    bS0 += 64; bS1 += 64; bS2 += 64; bS3 += 64;          \
  }

  STAGE6(sA0, sB0);                        // K-tile 0
  STAGE6(sA1, sB1);                        // K-tile 1
  asm volatile("s_waitcnt vmcnt(6)" ::: "memory");   // tile 0 landed
  __builtin_amdgcn_s_barrier();

  u16 *aC = sA0, *aN = sA1, *aSt = sA2;
  u16 *bC = sB0, *bN = sB1, *bSt = sB2;

  // fragment read offsets (u16 units); row&7 == li&7 for all frags
  int xr = li & 7;
  int aRow = (wr * 64 + li) * 64;
  int bRow = (wc * 64 + li) * 64;
  int ck0 = (quad ^ xr) * 8;               // kk=0 chunk (K 0..31)
  int ck1 = ((4 + quad) ^ xr) * 8;         // kk=1 chunk (K 32..63)

  for (int kt = 0; kt < 16; ++kt) {        // K=1024 / BK=64
    STAGE6(aSt, bSt);                      // K-tile kt+2 (garbage at tail, dead)
    bf16x8 aF0[4], aF1[4], bF0[4], bF1[4];
#pragma unroll
    for (int m = 0; m < 4; ++m) {
      aF0[m] = *(const bf16x8*)(aC + aRow + m * 1024 + ck0);
      aF1[m] = *(const bf16x8*)(aC + aRow + m * 1024 + ck1);
    }
#pragma unroll
    for (int n = 0; n < 4; ++n) {
      bF0[n] = *(const bf16x8*)(bC + bRow + n * 1024 + ck0);
      bF1[n] = *(const bf16x8*)(bC + bRow + n * 1024 + ck1);
    }
#pragma unroll
    for (int m = 0; m < 4; ++m)
#pragma unroll
      for (int n = 0; n < 4; ++n) {
        acc[m][n] = __builtin_amdgcn_mfma_f32_16x16x32_bf16(aF0[m], bF0[n], acc[m][n], 0, 0, 0);
        acc[m][n] = __builtin_amdgcn_mfma_f32_16x16x32_bf16(aF1[m], bF1[n], acc[m][n], 0, 0, 0);
      }
    // kt+1's 6 loads drained (12 outstanding -> 6); kt+2's stay in flight.
    asm volatile("s_waitcnt vmcnt(6)" ::: "memory");
    __builtin_amdgcn_s_barrier();
    u16* t;
    t = aC; aC = aN; aN = aSt; aSt = t;
    t = bC; bC = bN; bN = bSt; bSt = t;
  }
#undef STAGE6
}

// ---------------------------------------------------------------------------
// QKV GEMM, all batches: X[8192,1024] @ watT[3072,1024]^T. 128x256 tiles,
// grid 64x12 = 768 blocks = 3.0/CU exact. which (Q/K/V) uniform per block.
// ---------------------------------------------------------------------------
__global__ __launch_bounds__(512, 2) void gemm_qkv(const u16* __restrict__ X,
                                                   const u16* __restrict__ WT,
                                                   u16* __restrict__ Qb,
                                                   u16* __restrict__ Kb,
                                                   u16* __restrict__ Vt) {
  __shared__ __attribute__((aligned(16))) u16 sA[3][128 * 64];   // 48 KB
  __shared__ __attribute__((aligned(16))) u16 sB[3][256 * 64];   // 96 KB
  f32x4 acc[4][4];
  int m0 = blockIdx.x * 128, n0 = blockIdx.y * 256;
  gemm_mainloop(X, WT, m0, n0, sA[0], sA[1], sA[2], sB[0], sB[1], sB[2], acc);

  int tid = threadIdx.x;
  int w = tid >> 6, l = tid & 63, li = l & 15, quad = l >> 4;
  int wm = (w >> 2) * 64, wn = (w & 3) * 64;
#pragma unroll
  for (int i = 0; i < 4; ++i)
#pragma unroll
    for (int j = 0; j < 4; ++j) {
      int n = n0 + wn + j * 16 + li;
      int which = n >> 10, cc = n & (C_ - 1);
      int h = cc >> 6, d = cc & (HD_ - 1);
      int mb = m0 + wm + i * 16 + quad * 4;
      int b = mb >> 11, t0 = mb & (T_ - 1);
      if (which == 2) {
        u16 tv[4] = {f2bf(acc[i][j][0]), f2bf(acc[i][j][1]),
                     f2bf(acc[i][j][2]), f2bf(acc[i][j][3])};
        *(uint2*)(Vt + ((size_t)(b * NH_ + h) * HD_ + d) * T_ + t0) = *(const uint2*)tv;
      } else {
        u16* dst = (which == 0) ? Qb : Kb;
#pragma unroll
        for (int r = 0; r < 4; ++r)
          dst[((size_t)(b * NH_ + h) * T_ + t0 + r) * HD_ + d] = f2bf(acc[i][j][r]);
      }
    }
}

// ---------------------------------------------------------------------------
// Proj GEMM, all batches: Y[8192,1024] @ wprojT[1024,1024]^T -> f32 out.
// grid 64x4 = 256 blocks = 1.0/CU exact.
// ---------------------------------------------------------------------------
__global__ __launch_bounds__(512, 2) void gemm_proj(const u16* __restrict__ Y,
                                                    const u16* __restrict__ WT,
                                                    float* __restrict__ Out) {
  __shared__ __attribute__((aligned(16))) u16 sA[3][128 * 64];
  __shared__ __attribute__((aligned(16))) u16 sB[3][256 * 64];
  f32x4 acc[4][4];
  int m0 = blockIdx.x * 128, n0 = blockIdx.y * 256;
  gemm_mainloop(Y, WT, m0, n0, sA[0], sA[1], sA[2], sB[0], sB[1], sB[2], acc);

  int tid = threadIdx.x;
  int w = tid >> 6, l = tid & 63, li = l & 15, quad = l >> 4;
  int wm = (w >> 2) * 64, wn = (w & 3) * 64;
#pragma unroll
  for (int i = 0; i < 4; ++i)
#pragma unroll
    for (int j = 0; j < 4; ++j)
#pragma unroll
      for (int r = 0; r < 4; ++r) {
        int m = m0 + wm + i * 16 + quad * 4 + r;
        int n = n0 + wn + j * 16 + li;
        Out[(size_t)m * C_ + n] = acc[i][j][r];
      }
}

// ---------------------------------------------------------------------------
// Flash attention v9 (round 8 verified, 73 us): 32 q-rows/wave, 1024 skewed
// blocks (4/CU resident), swapped 32x32 QK^T, in-register softmax, max3
// row-max, defer-max, cvt_pk+permlane P-fragments. UNCHANGED this round.
// ---------------------------------------------------------------------------
__global__ __launch_bounds__(256, 2) void attn_k(const u16* __restrict__ Q,
                                                 const u16* __restrict__ K,
                                                 const u16* __restrict__ Vt,
                                                 u16* __restrict__ Y) {
  int bh = blockIdx.x;
  int qt = 15 - (int)blockIdx.y;           // heavy q-tiles dispatched first
  int tid = threadIdx.x;
  int w = tid >> 6, l = tid & 63;
  int l31 = l & 31, hi = l >> 5;
  int qb = qt * 128 + w * 32;              // this wave's 32-row q base
  int qg = qb + l31;                       // this lane's q-row

  __shared__ __attribute__((aligned(16))) u16 sK[2][64 * 64];
  __shared__ __attribute__((aligned(16))) u16 sV[2][64 * 64];

  const u16* kbase = K + (size_t)bh * T_ * HD_;
  const u16* vbase = Vt + (size_t)bh * HD_ * T_;

  // Q fragments (B-operand of S^T = K*Q^T): lane holds Q[qb+l31][16c+8hi+jj]
  bf16x8 qf[4];
  {
    const u16* qp = Q + ((size_t)bh * T_ + qg) * HD_ + hi * 8;
#pragma unroll
    for (int c = 0; c < 4; ++c) qf[c] = *(const bf16x8*)(qp + c * 16);
  }

  f32x16 o[2];
#pragma unroll
  for (int dt = 0; dt < 2; ++dt)
#pragma unroll
    for (int r = 0; r < 16; ++r) o[dt][r] = 0.f;
  float mrow = -1e30f, lsum = 0.f;
  const float csc = 0.125f * 1.44269504088896f;  // 1/sqrt(64) * log2(e)

  int nkv = 2 * qt + 2;

  // staging offsets (precomputed once; bases incremented per tile)
  int koff[2], voff[2], ldst[2];
  {
    int r0 = tid >> 3, c0_ = tid & 7;
#pragma unroll
    for (int rr = 0; rr < 2; ++rr) {
      int row = rr * 32 + r0;
      int cs = (c0_ ^ (row & 7)) * 8;      // source-side XOR swizzle, 16B granule
      koff[rr] = row * HD_ + cs;
      voff[rr] = row * T_ + cs;
      ldst[rr] = (rr * 256 + tid) * 8;
    }
  }
  const u16* kst = kbase;
  const u16* vst = vbase;
#define STAGE(buf)                                        \
  {                                                       \
    gload16(kst + koff[0], sK[buf] + ldst[0]);            \
    gload16(vst + voff[0], sV[buf] + ldst[0]);            \
    gload16(kst + koff[1], sK[buf] + ldst[1]);            \
    gload16(vst + voff[1], sV[buf] + ldst[1]);            \
    kst += 64 * HD_; vst += 64;                           \
  }

  STAGE(0);
  __syncthreads();

  int cur = 0;
  for (int kvt = 0; kvt < nkv; ++kvt) {
    int kv0 = kvt * 64;
    if (kvt + 1 < nkv) STAGE(cur ^ 1);

    bool aq = (kv0 <= qb + 31);            // wave has work this tile
    bool a1 = (kv0 + 32 <= qb + 31);       // second kv-half active
    if (aq) {
      // K fragments (A-operand): lane holds K[kv0+32s+l31][16c+8hi+jj]
      bf16x8 kf0[4], kf1[4];
#pragma unroll
      for (int c = 0; c < 4; ++c) {
        int row = l31;
        int c16 = (2 * c + hi) ^ (row & 7);
        kf0[c] = *(const bf16x8*)(sK[cur] + row * 64 + c16 * 8);
      }
      if (a1) {
#pragma unroll
        for (int c = 0; c < 4; ++c) {
          int row = 32 + l31;
          int c16 = (2 * c + hi) ^ (row & 7);
          kf1[c] = *(const bf16x8*)(sK[cur] + row * 64 + c16 * 8);
        }
      }

      f32x16 st0, st1;
#pragma unroll
      for (int r = 0; r < 16; ++r) { st0[r] = 0.f; st1[r] = 0.f; }
      __builtin_amdgcn_s_setprio(1);
#pragma unroll
      for (int c = 0; c < 4; ++c)
        st0 = __builtin_amdgcn_mfma_f32_32x32x16_bf16(kf0[c], qf[c], st0, 0, 0, 0);
      if (a1) {
#pragma unroll
        for (int c = 0; c < 4; ++c)
          st1 = __builtin_amdgcn_mfma_f32_32x32x16_bf16(kf1[c], qf[c], st1, 0, 0, 0);
      }
      __builtin_amdgcn_s_setprio(0);

      if (kv0 + 63 > qb) {                 // diagonal band: causal mask
#pragma unroll
        for (int r = 0; r < 16; ++r) {
          int kvg = kv0 + (r & 3) + 8 * (r >> 2) + 4 * hi;
          if (kvg > qg) st0[r] = -1e30f;
          if (a1 && kvg + 32 > qg) st1[r] = -1e30f;
        }
      }

      // row max via max3 tree (lane owns q-row; lane^32 has other kv half)
      float ml = max3f(st0[0], st0[1], st0[2]);
#pragma unroll
      for (int r = 3; r < 15; r += 2) ml = max3f(ml, st0[r], st0[r + 1]);
      ml = fmaxf(ml, st0[15]);
      if (a1) {
#pragma unroll
        for (int r = 0; r < 16; r += 2) ml = max3f(ml, st1[r], st1[r + 1]);
      }
      float mt = fmaxf(ml, __shfl_xor(ml, 32));
      float g = (mt - mrow) * csc;
      if (!__all(g <= 8.0f)) {             // defer-max: rescale only on growth
        float mnew = fmaxf(mrow, mt);
        float alpha = exp2f((mrow - mnew) * csc);
        mrow = mnew;
        lsum *= alpha;
#pragma unroll
        for (int r = 0; r < 16; ++r) {
          int qlr = (r & 3) + 8 * (r >> 2) + 4 * hi;
          float ar = __shfl(alpha, qlr);
          o[0][r] *= ar;
          o[1][r] *= ar;
        }
      }

      float mc = mrow * csc;
      float ls = 0.f;
#pragma unroll
      for (int r = 0; r < 16; ++r) {
        float p = exp2f(__builtin_fmaf(st0[r], csc, -mc));
        ls += p; st0[r] = p;
      }
      if (a1) {
#pragma unroll
        for (int r = 0; r < 16; ++r) {
          float p = exp2f(__builtin_fmaf(st1[r], csc, -mc));
          ls += p; st1[r] = p;
        }
      }
      lsum += ls;

      // pack to bf16 pairs (consecutive kv) and build A-fragments in-place
      union { unsigned uu[16]; bf16x8 v[4]; } pu;
#pragma unroll
      for (int k = 0; k < 8; ++k)
        asm("v_cvt_pk_bf16_f32 %0, %1, %2"
            : "=v"(pu.uu[k]) : "v"(st0[2 * k]), "v"(st0[2 * k + 1]));
      if (a1) {
#pragma unroll
        for (int k = 0; k < 8; ++k)
          asm("v_cvt_pk_bf16_f32 %0, %1, %2"
              : "=v"(pu.uu[8 + k]) : "v"(st1[2 * k]), "v"(st1[2 * k + 1]));
      }
#pragma unroll
      for (int h2 = 0; h2 < 2; ++h2) {
        PSWAP(pu.uu[4 * h2 + 0], pu.uu[4 * h2 + 2]);
        PSWAP(pu.uu[4 * h2 + 1], pu.uu[4 * h2 + 3]);
      }
      if (a1) {
#pragma unroll
        for (int h2 = 0; h2 < 2; ++h2) {
          PSWAP(pu.uu[8 + 4 * h2 + 0], pu.uu[8 + 4 * h2 + 2]);
          PSWAP(pu.uu[8 + 4 * h2 + 1], pu.uu[8 + 4 * h2 + 3]);
        }
      }

      // PV: O[q][d] += P[q][kv] * V[kv][d]
      __builtin_amdgcn_s_setprio(1);
#pragma unroll
      for (int dt = 0; dt < 2; ++dt) {
        bf16x8 vf[4];
#pragma unroll
        for (int c = 0; c < 4; ++c) {
          int row = 32 * dt + l31;
          int c16 = (2 * c + hi) ^ (row & 7);
          vf[c] = *(const bf16x8*)(sV[cur] + row * 64 + c16 * 8);
        }
#pragma unroll
        for (int c = 0; c < 4; ++c) {
          if (c >= 2 && !a1) continue;
          o[dt] = __builtin_amdgcn_mfma_f32_32x32x16_bf16(pu.v[c], vf[c], o[dt], 0, 0, 0);
        }
      }
      __builtin_amdgcn_s_setprio(0);
    }

    __syncthreads();   // drains prefetch vmcnt + guards buffer swap
    cur ^= 1;
  }

  // epilogue: combine partner lsum halves, normalize, store
  int b = bh >> 4, h = bh & (NH_ - 1);
  float lt = lsum + __shfl_xor(lsum, 32);
  float rv = 1.0f / fmaxf(lt, 1e-20f);
#pragma unroll
  for (int r = 0; r < 16; ++r) {
    int qlr = (r & 3) + 8 * (r >> 2) + 4 * hi;
    float rr = __shfl(rv, qlr);
    int qq = qb + qlr;
    size_t base = ((size_t)b * T_ + qq) * C_ + h * HD_;
    Y[base + l31]      = f2bf(o[0][r] * rr);
    Y[base + 32 + l31] = f2bf(o[1][r] * rr);
  }
#undef STAGE
}

// ---------------------------------------------------------------------------
extern "C" void kernel_launch(void* const* d_in, const int* in_sizes, int n_in,
                              void* d_out, int out_size, void* d_ws, size_t ws_size,
                              hipStream_t stream) {
  (void)in_sizes; (void)n_in; (void)out_size; (void)ws_size;
  const float* x      = (const float*)d_in[0];   // [B,T,C] f32
  const float* w_attn = (const float*)d_in[1];   // [C,3C]  f32
  const float* w_proj = (const float*)d_in[2];   // [C,C]   f32
  float* out = (float*)d_out;                    // [B,T,C] f32

  const size_t NTOK = (size_t)B_ * T_ * C_;      // 8.39M elems
  u16* watT   = (u16*)d_ws;                      // 3.15M
  u16* wprojT = watT   + (size_t)3 * C_ * C_;    // 1.05M
  u16* xbf    = wprojT + (size_t)C_ * C_;        // 8.39M (yb overlays this)
  u16* qb     = xbf  + NTOK;                     // 8.39M [b,h,t,d]
  u16* kb     = qb   + NTOK;                     // 8.39M [b,h,t,d]
  u16* vtb    = kb   + NTOK;                     // 8.39M [b,h,d,t]
  u16* yb     = xbf;                             // overlay: xbf dead after qkv
  // total ws: 37.8M u16 = 75.5 MB

  transpose_w<<<dim3(16, 48), 256, 0, stream>>>(w_attn, watT, C_, 3 * C_);
  transpose_w<<<dim3(16, 16), 256, 0, stream>>>(w_proj, wprojT, C_, C_);
  convert_x<<<dim3(4096), 256, 0, stream>>>(x, xbf);
  gemm_qkv<<<dim3(64, 12), 512, 0, stream>>>(xbf, watT, qb, kb, vtb);
  attn_k<<<dim3(64, 16), 256, 0, stream>>>(qb, kb, vtb, yb);
  gemm_proj<<<dim3(64, 4), 512, 0, stream>>>(yb, wprojT, out);
}

// Round 10
// 229.186 us; speedup vs baseline: 1.1045x; 1.1045x over previous
//
#include <hip/hip_runtime.h>

typedef unsigned short u16;
typedef short bf16x8 __attribute__((ext_vector_type(8)));
typedef float f32x4 __attribute__((ext_vector_type(4)));
typedef float f32x16 __attribute__((ext_vector_type(16)));

#define B_  4
#define T_  2048
#define C_  1024
#define NH_ 16
#define HD_ 64

// async global->LDS, 16B/lane; LDS dest = wave-uniform base + lane*16.
__device__ __forceinline__ void gload16(const u16* g, u16* lds) {
  __builtin_amdgcn_global_load_lds(
      (const __attribute__((address_space(1))) void*)g,
      (__attribute__((address_space(3))) void*)lds, 16, 0, 0);
}

__device__ __forceinline__ u16 f2bf(float f) {  // RNE float->bf16
  union { float f; unsigned u; } x; x.f = f;
  unsigned r = x.u + 0x7fffu + ((x.u >> 16) & 1u);
  return (u16)(r >> 16);
}

__device__ __forceinline__ float max3f(float a, float b, float c) {
  return fmaxf(fmaxf(a, b), c);   // clang fuses to v_max3_f32
}

// v_permlane32_swap_b32: used ONLY for the P-fragment shuffle (distinct-value
// operands, verified rounds 3-5). Round 6 showed same-value cross-half
// reductions via PSWAP produce NaN — those use __shfl_xor(,32).
#define PSWAP(a, b) asm("v_permlane32_swap_b32 %0, %1" : "+v"(a), "+v"(b))

// ---------------------------------------------------------------------------
// x (f32, all batches) -> bf16
// ---------------------------------------------------------------------------
__global__ __launch_bounds__(256) void convert_x(const float* __restrict__ in,
                                                 u16* __restrict__ out) {
  int i = (blockIdx.x * 256 + threadIdx.x) * 8;
  float4 a = *(const float4*)(in + i);
  float4 b = *(const float4*)(in + i + 4);
  u16 t[8] = {f2bf(a.x), f2bf(a.y), f2bf(a.z), f2bf(a.w),
              f2bf(b.x), f2bf(b.y), f2bf(b.z), f2bf(b.w)};
  *(uint4*)(out + i) = *(const uint4*)t;
}

// ---------------------------------------------------------------------------
// Weight transpose+convert: f32 [R][Cc] -> bf16 [Cc][R]
// ---------------------------------------------------------------------------
__global__ __launch_bounds__(256) void transpose_w(const float* __restrict__ in,
                                                   u16* __restrict__ out,
                                                   int R, int Cc) {
  int r0 = blockIdx.x * 64, c0 = blockIdx.y * 64;
  __shared__ __attribute__((aligned(16))) u16 tile[64][72];
  int tid = threadIdx.x;
#pragma unroll
  for (int it = 0; it < 4; ++it) {
    int chunk = it * 256 + tid;          // 0..1023
    int row = chunk >> 4, c4 = chunk & 15;
    float4 v = *(const float4*)(in + (size_t)(r0 + row) * Cc + c0 + c4 * 4);
    tile[row][c4 * 4 + 0] = f2bf(v.x);
    tile[row][c4 * 4 + 1] = f2bf(v.y);
    tile[row][c4 * 4 + 2] = f2bf(v.z);
    tile[row][c4 * 4 + 3] = f2bf(v.w);
  }
  __syncthreads();
#pragma unroll
  for (int it = 0; it < 2; ++it) {
    int chunk = it * 256 + tid;
    int row = chunk >> 3, c8 = chunk & 7;
    uint4 v; u16* tv = (u16*)&v;
#pragma unroll
    for (int k = 0; k < 8; ++k) tv[k] = tile[c8 * 8 + k][row];
    *(uint4*)(out + (size_t)(c0 + row) * R + r0 + c8 * 8) = v;
  }
}

// ---------------------------------------------------------------------------
// BT GEMM mainloop v3: 128x128 tile, BK=64, 4 waves (2Mx2N), double-buffered
// LDS (2 x 32KB = 64KB -> 2 independent blocks/CU stagger their phases: when
// one block is in its vmcnt/barrier rendezvous the other feeds LDS + MFMA —
// round 9's 1-block/CU 144KB layout stalled 74% in lockstep).
// Counted vmcnt(8): gate waits until only the 8 just-issued loads of tile
// kt+1 are outstanding => tile kt fully landed; never drains to 0.
// XOR-swizzle via pre-swizzled global source (round-9 verified addressing).
// Tail iteration stages garbage (stays inside workspace; round-9 verified).
// ---------------------------------------------------------------------------
__device__ __forceinline__ void gemm_mainloop(const u16* __restrict__ A,
                                              const u16* __restrict__ Bt,
                                              int m0, int n0,
                                              u16* s0, u16* s1,
                                              f32x4 acc[4][4]) {
  int tid = threadIdx.x;                   // 256 threads
  int w = tid >> 6, l = tid & 63, li = l & 15, quad = l >> 4;
  int wr = w >> 1, wc = w & 1;

  f32x4 zero = {0.f, 0.f, 0.f, 0.f};
#pragma unroll
  for (int m = 0; m < 4; ++m)
#pragma unroll
    for (int n = 0; n < 4; ++n) acc[m][n] = zero;

  // staging: 4 issues x 32 rows cover 128 rows for each of A,B.
  int srow = tid >> 3;                     // 0..31
  int sc = (tid & 7) ^ (srow & 7);         // pre-swizzled source chunk
  const u16* aS[4];
  const u16* bS[4];
#pragma unroll
  for (int i = 0; i < 4; ++i) {
    aS[i] = A + (size_t)(m0 + i * 32 + srow) * C_ + sc * 8;
    bS[i] = Bt + (size_t)(n0 + i * 32 + srow) * C_ + sc * 8;
  }
  int ldOff = tid * 8;

#define STAGE8(sbuf)                                      \
  {                                                       \
    _Pragma("unroll")                                     \
    for (int i = 0; i < 4; ++i) {                         \
      gload16(aS[i], (sbuf) + i * 2048 + ldOff);          \
      gload16(bS[i], (sbuf) + 8192 + i * 2048 + ldOff);   \
      aS[i] += 64; bS[i] += 64;                           \
    }                                                     \
  }

  // fragment read offsets; row&7 == li&7 for all fragment rows
  int xr = li & 7;
  int ck0 = (quad ^ xr) * 8;               // kk=0 chunk (K 0..31)
  int ck1 = ((4 + quad) ^ xr) * 8;         // kk=1 chunk (K 32..63)
  int aRow = (wr * 64 + li) * 64;
  int bRow = 8192 + (wc * 64 + li) * 64;

  u16* scur = s0;
  u16* snxt = s1;
  STAGE8(scur);                            // tile 0

  for (int kt = 0; kt < 16; ++kt) {        // K=1024 / BK=64
    STAGE8(snxt);                          // tile kt+1 (garbage at kt=15, dead)
    asm volatile("s_waitcnt vmcnt(8)" ::: "memory");   // tile kt landed
    __builtin_amdgcn_s_barrier();
    asm volatile("" ::: "memory");

    bf16x8 aF0[4], aF1[4], bF0[4], bF1[4];
#pragma unroll
    for (int m = 0; m < 4; ++m) {
      aF0[m] = *(const bf16x8*)(scur + aRow + m * 1024 + ck0);
      aF1[m] = *(const bf16x8*)(scur + aRow + m * 1024 + ck1);
    }
#pragma unroll
    for (int n = 0; n < 4; ++n) {
      bF0[n] = *(const bf16x8*)(scur + bRow + n * 1024 + ck0);
      bF1[n] = *(const bf16x8*)(scur + bRow + n * 1024 + ck1);
    }
    __builtin_amdgcn_s_setprio(1);
#pragma unroll
    for (int m = 0; m < 4; ++m)
#pragma unroll
      for (int n = 0; n < 4; ++n) {
        acc[m][n] = __builtin_amdgcn_mfma_f32_16x16x32_bf16(aF0[m], bF0[n], acc[m][n], 0, 0, 0);
        acc[m][n] = __builtin_amdgcn_mfma_f32_16x16x32_bf16(aF1[m], bF1[n], acc[m][n], 0, 0, 0);
      }
    __builtin_amdgcn_s_setprio(0);

    asm volatile("" ::: "memory");
    __builtin_amdgcn_s_barrier();          // reads done -> next overwrite safe
    asm volatile("" ::: "memory");
    u16* t = scur; scur = snxt; snxt = t;
  }
#undef STAGE8
}

// ---------------------------------------------------------------------------
// QKV GEMM, all batches: X[8192,1024] @ watT[3072,1024]^T. 128x128 tiles,
// grid 64x24 = 1536 blocks = 6/CU (2 resident, 3 clean rounds).
// ---------------------------------------------------------------------------
__global__ __launch_bounds__(256, 2) void gemm_qkv(const u16* __restrict__ X,
                                                   const u16* __restrict__ WT,
                                                   u16* __restrict__ Qb,
                                                   u16* __restrict__ Kb,
                                                   u16* __restrict__ Vt) {
  __shared__ __attribute__((aligned(16))) u16 sBuf[2][128 * 64 * 2];  // 64 KB
  f32x4 acc[4][4];
  int m0 = blockIdx.x * 128, n0 = blockIdx.y * 128;
  gemm_mainloop(X, WT, m0, n0, sBuf[0], sBuf[1], acc);

  int tid = threadIdx.x;
  int w = tid >> 6, l = tid & 63, li = l & 15, quad = l >> 4;
  int wm = (w >> 1) * 64, wn = (w & 1) * 64;
#pragma unroll
  for (int i = 0; i < 4; ++i)
#pragma unroll
    for (int j = 0; j < 4; ++j) {
      int n = n0 + wn + j * 16 + li;
      int which = n >> 10, cc = n & (C_ - 1);
      int h = cc >> 6, d = cc & (HD_ - 1);
      int mb = m0 + wm + i * 16 + quad * 4;
      int b = mb >> 11, t0 = mb & (T_ - 1);
      if (which == 2) {
        u16 tv[4] = {f2bf(acc[i][j][0]), f2bf(acc[i][j][1]),
                     f2bf(acc[i][j][2]), f2bf(acc[i][j][3])};
        *(uint2*)(Vt + ((size_t)(b * NH_ + h) * HD_ + d) * T_ + t0) = *(const uint2*)tv;
      } else {
        u16* dst = (which == 0) ? Qb : Kb;
#pragma unroll
        for (int r = 0; r < 4; ++r)
          dst[((size_t)(b * NH_ + h) * T_ + t0 + r) * HD_ + d] = f2bf(acc[i][j][r]);
      }
    }
}

// ---------------------------------------------------------------------------
// Proj GEMM, all batches: Y[8192,1024] @ wprojT[1024,1024]^T -> f32 out.
// grid 64x8 = 512 blocks = 2/CU exact, one round.
// ---------------------------------------------------------------------------
__global__ __launch_bounds__(256, 2) void gemm_proj(const u16* __restrict__ Y,
                                                    const u16* __restrict__ WT,
                                                    float* __restrict__ Out) {
  __shared__ __attribute__((aligned(16))) u16 sBuf[2][128 * 64 * 2];  // 64 KB
  f32x4 acc[4][4];
  int m0 = blockIdx.x * 128, n0 = blockIdx.y * 128;
  gemm_mainloop(Y, WT, m0, n0, sBuf[0], sBuf[1], acc);

  int tid = threadIdx.x;
  int w = tid >> 6, l = tid & 63, li = l & 15, quad = l >> 4;
  int wm = (w >> 1) * 64, wn = (w & 1) * 64;
#pragma unroll
  for (int i = 0; i < 4; ++i)
#pragma unroll
    for (int j = 0; j < 4; ++j)
#pragma unroll
      for (int r = 0; r < 4; ++r) {
        int m = m0 + wm + i * 16 + quad * 4 + r;
        int n = n0 + wn + j * 16 + li;
        Out[(size_t)m * C_ + n] = acc[i][j][r];
      }
}

// ---------------------------------------------------------------------------
// Flash attention v9 (round 8 verified, 73 us): 32 q-rows/wave, 1024 skewed
// blocks (4/CU resident), swapped 32x32 QK^T, in-register softmax, max3
// row-max, defer-max, cvt_pk+permlane P-fragments. UNCHANGED.
// ---------------------------------------------------------------------------
__global__ __launch_bounds__(256, 2) void attn_k(const u16* __restrict__ Q,
                                                 const u16* __restrict__ K,
                                                 const u16* __restrict__ Vt,
                                                 u16* __restrict__ Y) {
  int bh = blockIdx.x;
  int qt = 15 - (int)blockIdx.y;           // heavy q-tiles dispatched first
  int tid = threadIdx.x;
  int w = tid >> 6, l = tid & 63;
  int l31 = l & 31, hi = l >> 5;
  int qb = qt * 128 + w * 32;              // this wave's 32-row q base
  int qg = qb + l31;                       // this lane's q-row

  __shared__ __attribute__((aligned(16))) u16 sK[2][64 * 64];
  __shared__ __attribute__((aligned(16))) u16 sV[2][64 * 64];

  const u16* kbase = K + (size_t)bh * T_ * HD_;
  const u16* vbase = Vt + (size_t)bh * HD_ * T_;

  // Q fragments (B-operand of S^T = K*Q^T): lane holds Q[qb+l31][16c+8hi+jj]
  bf16x8 qf[4];
  {
    const u16* qp = Q + ((size_t)bh * T_ + qg) * HD_ + hi * 8;
#pragma unroll
    for (int c = 0; c < 4; ++c) qf[c] = *(const bf16x8*)(qp + c * 16);
  }

  f32x16 o[2];
#pragma unroll
  for (int dt = 0; dt < 2; ++dt)
#pragma unroll
    for (int r = 0; r < 16; ++r) o[dt][r] = 0.f;
  float mrow = -1e30f, lsum = 0.f;
  const float csc = 0.125f * 1.44269504088896f;  // 1/sqrt(64) * log2(e)

  int nkv = 2 * qt + 2;

  // staging offsets (precomputed once; bases incremented per tile)
  int koff[2], voff[2], ldst[2];
  {
    int r0 = tid >> 3, c0_ = tid & 7;
#pragma unroll
    for (int rr = 0; rr < 2; ++rr) {
      int row = rr * 32 + r0;
      int cs = (c0_ ^ (row & 7)) * 8;      // source-side XOR swizzle, 16B granule
      koff[rr] = row * HD_ + cs;
      voff[rr] = row * T_ + cs;
      ldst[rr] = (rr * 256 + tid) * 8;
    }
  }
  const u16* kst = kbase;
  const u16* vst = vbase;
#define STAGE(buf)                                        \
  {                                                       \
    gload16(kst + koff[0], sK[buf] + ldst[0]);            \
    gload16(vst + voff[0], sV[buf] + ldst[0]);            \
    gload16(kst + koff[1], sK[buf] + ldst[1]);            \
    gload16(vst + voff[1], sV[buf] + ldst[1]);            \
    kst += 64 * HD_; vst += 64;                           \
  }

  STAGE(0);
  __syncthreads();

  int cur = 0;
  for (int kvt = 0; kvt < nkv; ++kvt) {
    int kv0 = kvt * 64;
    if (kvt + 1 < nkv) STAGE(cur ^ 1);

    bool aq = (kv0 <= qb + 31);            // wave has work this tile
    bool a1 = (kv0 + 32 <= qb + 31);       // second kv-half active
    if (aq) {
      // K fragments (A-operand): lane holds K[kv0+32s+l31][16c+8hi+jj]
      bf16x8 kf0[4], kf1[4];
#pragma unroll
      for (int c = 0; c < 4; ++c) {
        int row = l31;
        int c16 = (2 * c + hi) ^ (row & 7);
        kf0[c] = *(const bf16x8*)(sK[cur] + row * 64 + c16 * 8);
      }
      if (a1) {
#pragma unroll
        for (int c = 0; c < 4; ++c) {
          int row = 32 + l31;
          int c16 = (2 * c + hi) ^ (row & 7);
          kf1[c] = *(const bf16x8*)(sK[cur] + row * 64 + c16 * 8);
        }
      }

      f32x16 st0, st1;
#pragma unroll
      for (int r = 0; r < 16; ++r) { st0[r] = 0.f; st1[r] = 0.f; }
      __builtin_amdgcn_s_setprio(1);
#pragma unroll
      for (int c = 0; c < 4; ++c)
        st0 = __builtin_amdgcn_mfma_f32_32x32x16_bf16(kf0[c], qf[c], st0, 0, 0, 0);
      if (a1) {
#pragma unroll
        for (int c = 0; c < 4; ++c)
          st1 = __builtin_amdgcn_mfma_f32_32x32x16_bf16(kf1[c], qf[c], st1, 0, 0, 0);
      }
      __builtin_amdgcn_s_setprio(0);

      if (kv0 + 63 > qb) {                 // diagonal band: causal mask
#pragma unroll
        for (int r = 0; r < 16; ++r) {
          int kvg = kv0 + (r & 3) + 8 * (r >> 2) + 4 * hi;
          if (kvg > qg) st0[r] = -1e30f;
          if (a1 && kvg + 32 > qg) st1[r] = -1e30f;
        }
      }

      // row max via max3 tree (lane owns q-row; lane^32 has other kv half)
      float ml = max3f(st0[0], st0[1], st0[2]);
#pragma unroll
      for (int r = 3; r < 15; r += 2) ml = max3f(ml, st0[r], st0[r + 1]);
      ml = fmaxf(ml, st0[15]);
      if (a1) {
#pragma unroll
        for (int r = 0; r < 16; r += 2) ml = max3f(ml, st1[r], st1[r + 1]);
      }
      float mt = fmaxf(ml, __shfl_xor(ml, 32));
      float g = (mt - mrow) * csc;
      if (!__all(g <= 8.0f)) {             // defer-max: rescale only on growth
        float mnew = fmaxf(mrow, mt);
        float alpha = exp2f((mrow - mnew) * csc);
        mrow = mnew;
        lsum *= alpha;
#pragma unroll
        for (int r = 0; r < 16; ++r) {
          int qlr = (r & 3) + 8 * (r >> 2) + 4 * hi;
          float ar = __shfl(alpha, qlr);
          o[0][r] *= ar;
          o[1][r] *= ar;
        }
      }

      float mc = mrow * csc;
      float ls = 0.f;
#pragma unroll
      for (int r = 0; r < 16; ++r) {
        float p = exp2f(__builtin_fmaf(st0[r], csc, -mc));
        ls += p; st0[r] = p;
      }
      if (a1) {
#pragma unroll
        for (int r = 0; r < 16; ++r) {
          float p = exp2f(__builtin_fmaf(st1[r], csc, -mc));
          ls += p; st1[r] = p;
        }
      }
      lsum += ls;

      // pack to bf16 pairs (consecutive kv) and build A-fragments in-place
      union { unsigned uu[16]; bf16x8 v[4]; } pu;
#pragma unroll
      for (int k = 0; k < 8; ++k)
        asm("v_cvt_pk_bf16_f32 %0, %1, %2"
            : "=v"(pu.uu[k]) : "v"(st0[2 * k]), "v"(st0[2 * k + 1]));
      if (a1) {
#pragma unroll
        for (int k = 0; k < 8; ++k)
          asm("v_cvt_pk_bf16_f32 %0, %1, %2"
              : "=v"(pu.uu[8 + k]) : "v"(st1[2 * k]), "v"(st1[2 * k + 1]));
      }
#pragma unroll
      for (int h2 = 0; h2 < 2; ++h2) {
        PSWAP(pu.uu[4 * h2 + 0], pu.uu[4 * h2 + 2]);
        PSWAP(pu.uu[4 * h2 + 1], pu.uu[4 * h2 + 3]);
      }
      if (a1) {
#pragma unroll
        for (int h2 = 0; h2 < 2; ++h2) {
          PSWAP(pu.uu[8 + 4 * h2 + 0], pu.uu[8 + 4 * h2 + 2]);
          PSWAP(pu.uu[8 + 4 * h2 + 1], pu.uu[8 + 4 * h2 + 3]);
        }
      }

      // PV: O[q][d] += P[q][kv] * V[kv][d]
      __builtin_amdgcn_s_setprio(1);
#pragma unroll
      for (int dt = 0; dt < 2; ++dt) {
        bf16x8 vf[4];
#pragma unroll
        for (int c = 0; c < 4; ++c) {
          int row = 32 * dt + l31;
          int c16 = (2 * c + hi) ^ (row & 7);
          vf[c] = *(const bf16x8*)(sV[cur] + row * 64 + c16 * 8);
        }
#pragma unroll
        for (int c = 0; c < 4; ++c) {
          if (c >= 2 && !a1) continue;
          o[dt] = __builtin_amdgcn_mfma_f32_32x32x16_bf16(pu.v[c], vf[c], o[dt], 0, 0, 0);
        }
      }
      __builtin_amdgcn_s_setprio(0);
    }

    __syncthreads();   // drains prefetch vmcnt + guards buffer swap
    cur ^= 1;
  }

  // epilogue: combine partner lsum halves, normalize, store
  int b = bh >> 4, h = bh & (NH_ - 1);
  float lt = lsum + __shfl_xor(lsum, 32);
  float rv = 1.0f / fmaxf(lt, 1e-20f);
#pragma unroll
  for (int r = 0; r < 16; ++r) {
    int qlr = (r & 3) + 8 * (r >> 2) + 4 * hi;
    float rr = __shfl(rv, qlr);
    int qq = qb + qlr;
    size_t base = ((size_t)b * T_ + qq) * C_ + h * HD_;
    Y[base + l31]      = f2bf(o[0][r] * rr);
    Y[base + 32 + l31] = f2bf(o[1][r] * rr);
  }
#undef STAGE
}

// ---------------------------------------------------------------------------
extern "C" void kernel_launch(void* const* d_in, const int* in_sizes, int n_in,
                              void* d_out, int out_size, void* d_ws, size_t ws_size,
                              hipStream_t stream) {
  (void)in_sizes; (void)n_in; (void)out_size; (void)ws_size;
  const float* x      = (const float*)d_in[0];   // [B,T,C] f32
  const float* w_attn = (const float*)d_in[1];   // [C,3C]  f32
  const float* w_proj = (const float*)d_in[2];   // [C,C]   f32
  float* out = (float*)d_out;                    // [B,T,C] f32

  const size_t NTOK = (size_t)B_ * T_ * C_;      // 8.39M elems
  u16* watT   = (u16*)d_ws;                      // 3.15M
  u16* wprojT = watT   + (size_t)3 * C_ * C_;    // 1.05M
  u16* xbf    = wprojT + (size_t)C_ * C_;        // 8.39M (yb overlays this)
  u16* qb     = xbf  + NTOK;                     // 8.39M [b,h,t,d]
  u16* kb     = qb   + NTOK;                     // 8.39M [b,h,t,d]
  u16* vtb    = kb   + NTOK;                     // 8.39M [b,h,d,t]
  u16* yb     = xbf;                             // overlay: xbf dead after qkv
  // total ws: 37.8M u16 = 75.5 MB

  transpose_w<<<dim3(16, 48), 256, 0, stream>>>(w_attn, watT, C_, 3 * C_);
  transpose_w<<<dim3(16, 16), 256, 0, stream>>>(w_proj, wprojT, C_, C_);
  convert_x<<<dim3(4096), 256, 0, stream>>>(x, xbf);
  gemm_qkv<<<dim3(64, 24), 256, 0, stream>>>(xbf, watT, qb, kb, vtb);
  attn_k<<<dim3(64, 16), 256, 0, stream>>>(qb, kb, vtb, yb);
  gemm_proj<<<dim3(64, 8), 256, 0, stream>>>(yb, wprojT, out);
}